// Round 1
// 745.176 us; speedup vs baseline: 1.2164x; 1.2164x over previous
//
#include <hip/hip_runtime.h>

// Problem constants (B=8, N=2048, H=2048, E=4, I=2048)
#define HDIM 2048
#define IDIM 2048
#define KD   2048
#define ME   4096   // tokens per expert (B*N/E)
#define NT   64     // K tiles of 32

// Workspace layout (requires >= 234,881,024 bytes):
//   xb    @ 0         : bf16 x regrouped [e][t][h], 64 MiB
//   w1t   @ 64 MiB    : bf16 gate_up^T  [e][d][h], 64 MiB
//   w2t   @ 128 MiB   : bf16 down^T     [e][h][i], 32 MiB
//   inter @ 160 MiB   : bf16 silu(g)*u  [e][t][i], 64 MiB

typedef __bf16 bf16x8 __attribute__((ext_vector_type(8)));
typedef float f32x4 __attribute__((ext_vector_type(4)));

__device__ __forceinline__ unsigned short f2bf(float f) {
  unsigned u = __builtin_bit_cast(unsigned, f);
  u += 0x7FFFu + ((u >> 16) & 1u);   // round-to-nearest-even
  return (unsigned short)(u >> 16);
}

__device__ __forceinline__ void gld16(const void* g, void* l) {
  __builtin_amdgcn_global_load_lds(
      (const __attribute__((address_space(1))) unsigned int*)g,
      (__attribute__((address_space(3))) unsigned int*)l, 16, 0, 0);
}

template<int N> __device__ __forceinline__ void wait_vmcnt() {
  asm volatile("s_waitcnt vmcnt(%0)" :: "i"(N) : "memory");
}

// ---- Kernel 1: convert x fp32 -> bf16, regroup rows per expert ----
__global__ void __launch_bounds__(256) pack_x(const float* __restrict__ x,
                                              unsigned short* __restrict__ xb) {
  const int row = blockIdx.x;            // 0..16383 = b*2048 + n
  const int n = row & 2047;
  const int b = row >> 11;
  const int e = n & 3, g = n >> 2;
  const float4* src = (const float4*)(x + (size_t)row * HDIM);
  unsigned short* dst = xb + ((size_t)e * ME + b * 512 + g) * HDIM;
  const int t = threadIdx.x;
  float4 v0 = src[2 * t];
  float4 v1 = src[2 * t + 1];
  uint4 pk;
  pk.x = (unsigned)f2bf(v0.x) | ((unsigned)f2bf(v0.y) << 16);
  pk.y = (unsigned)f2bf(v0.z) | ((unsigned)f2bf(v0.w) << 16);
  pk.z = (unsigned)f2bf(v1.x) | ((unsigned)f2bf(v1.y) << 16);
  pk.w = (unsigned)f2bf(v1.z) | ((unsigned)f2bf(v1.w) << 16);
  *(uint4*)(dst + 8 * t) = pk;
}

// ---- Kernel 2: transpose + cast fp32 (R x C) -> bf16 (C x R), per expert z ----
__global__ void __launch_bounds__(256) transpose_cvt(const float* __restrict__ src,
                                                     unsigned short* __restrict__ dst,
                                                     int R, int C) {
  __shared__ unsigned short tile[32][33];
  const size_t eo = (size_t)blockIdx.z * R * C;
  src += eo;
  dst += eo;
  const int c0 = blockIdx.x * 32, r0 = blockIdx.y * 32;
  const int tx = threadIdx.x & 31, ty = threadIdx.x >> 5;
#pragma unroll
  for (int j = 0; j < 4; ++j) {
    int r = r0 + ty + j * 8;
    tile[ty + j * 8][tx] = f2bf(src[(size_t)r * C + c0 + tx]);
  }
  __syncthreads();
#pragma unroll
  for (int j = 0; j < 4; ++j) {
    int c = c0 + ty + j * 8;
    dst[(size_t)c * R + r0 + tx] = tile[tx][ty + j * 8];
  }
}

// ==== Counted-vmcnt 4-slot pipeline GEMMs ====
// LDS: 4 slots x 32 KiB (A[256x32] @ +0, B[256x32] @ +16 KiB), st_16x32 swizzle:
//   element (row, c) lives at byte row*64 + (c ^ ((row&8)?16:0))*2  (linear gld16
//   dest, inverse-swizzled GLOBAL source, swizzled ds_read addr — m201/m173).
// Tile t in slot t&3. Tile t's body stages tile t+3 (slot of t-1: fully read,
// certified by tile t's top barrier). One s_waitcnt vmcnt(8) + one s_barrier per
// tile; vmcnt drains 8->4->0 over the last 3 tiles. 4 gld16/thread/tile.

// ---- Kernel 3 tile body: GEMM1 (A 256xK, gate 128 + up 128 cols per block) ----
template<int VMN, bool STG>
__device__ __forceinline__ void g1_tile(const unsigned short* S, int ab0, int bb0,
                                        const unsigned short*& ap0, const unsigned short*& ap1,
                                        const unsigned short*& bgp, const unsigned short*& bup,
                                        unsigned short* sb,
                                        f32x4 (&accg)[8][2], f32x4 (&accu)[8][2]) {
  wait_vmcnt<VMN>();                 // my stage-loads for this tile landed
  __builtin_amdgcn_s_barrier();      // everyone's landed; prev-tile reads done
  asm volatile("" ::: "memory");
  bf16x8 a[4], bg[2], bu[2];
#pragma unroll
  for (int i = 0; i < 4; ++i) a[i] = *(const bf16x8*)(S + ab0 + i * 512);
#pragma unroll
  for (int j = 0; j < 2; ++j) {
    bg[j] = *(const bf16x8*)(S + bb0 + j * 512);
    bu[j] = *(const bf16x8*)(S + bb0 + 4096 + j * 512);
  }
  if constexpr (STG) { gld16(ap0, sb); gld16(ap1, sb + 4096); }
  __builtin_amdgcn_s_setprio(1);
#pragma unroll
  for (int i = 0; i < 4; ++i)
#pragma unroll
    for (int j = 0; j < 2; ++j) {
      accg[i][j] = __builtin_amdgcn_mfma_f32_16x16x32_bf16(a[i], bg[j], accg[i][j], 0, 0, 0);
      accu[i][j] = __builtin_amdgcn_mfma_f32_16x16x32_bf16(a[i], bu[j], accu[i][j], 0, 0, 0);
    }
  __builtin_amdgcn_s_setprio(0);
  bf16x8 a2[4];
#pragma unroll
  for (int i = 0; i < 4; ++i) a2[i] = *(const bf16x8*)(S + ab0 + (i + 4) * 512);
  if constexpr (STG) {
    gld16(bgp, sb + 8192); gld16(bup, sb + 12288);
    ap0 += 32; ap1 += 32; bgp += 32; bup += 32;
  }
  __builtin_amdgcn_s_setprio(1);
#pragma unroll
  for (int i = 0; i < 4; ++i)
#pragma unroll
    for (int j = 0; j < 2; ++j) {
      accg[i + 4][j] = __builtin_amdgcn_mfma_f32_16x16x32_bf16(a2[i], bg[j], accg[i + 4][j], 0, 0, 0);
      accu[i + 4][j] = __builtin_amdgcn_mfma_f32_16x16x32_bf16(a2[i], bu[j], accu[i + 4][j], 0, 0, 0);
    }
  __builtin_amdgcn_s_setprio(0);
}

// ---- Kernel 3: GEMM1 + fused SiLU-gate. Block 256 M x 128 i-cols, 8 waves. ----
__global__ void __launch_bounds__(512) gemm1_silu(const unsigned short* __restrict__ xb,
                                                  const unsigned short* __restrict__ w1t,
                                                  unsigned short* __restrict__ inter) {
  __shared__ unsigned short SM[65536];   // 128 KiB: 4 slots x (A 8192 | B 8192) elems
  const int e = blockIdx.z;
  const int m0 = blockIdx.x * 256;
  const int c0 = blockIdx.y * 128;       // i-tile
  const int t = threadIdx.x;
  const int lane = t & 63;
  const int wave = t >> 6;
  const int wm = wave >> 2;              // 0..1 : 128-row half
  const int wn = wave & 3;               // 0..3 : 32-col quarter

  const unsigned short* xe = xb + (size_t)e * ME * KD;
  const unsigned short* we = w1t + (size_t)e * 4096 * KD;

  // staging: thread t -> row t/4, 16B chunk (t%4), inverse-swizzled source col
  const int srow = t >> 2;
  const int scol = ((t & 3) * 8) ^ ((t & 32) ? 16 : 0);
  const unsigned short* ap0 = xe + (size_t)(m0 + srow) * KD + scol;          // A rows 0..127
  const unsigned short* ap1 = ap0 + (size_t)128 * KD;                        // A rows 128..255
  const unsigned short* bgp = we + (size_t)(c0 + srow) * KD + scol;          // gate cols
  const unsigned short* bup = bgp + (size_t)2048 * KD;                       // up cols

  // ds_read bases (elements within slot), swizzled
  const int l15 = lane & 15;
  const int kqs = ((lane >> 4) * 8) ^ ((lane & 8) ? 16 : 0);
  const int ab0 = (wm * 128 + l15) * 32 + kqs;
  const int bb0 = 8192 + (wn * 32 + l15) * 32 + kqs;   // gate rows; up = +4096

  f32x4 accg[8][2] = {};
  f32x4 accu[8][2] = {};

  // prologue: stage tiles 0..2 into slots 0..2 (12 loads in flight)
#pragma unroll
  for (int s = 0; s < 3; ++s) {
    unsigned short* sb = SM + s * 16384 + t * 8;
    gld16(ap0, sb); gld16(ap1, sb + 4096); gld16(bgp, sb + 8192); gld16(bup, sb + 12288);
    ap0 += 32; ap1 += 32; bgp += 32; bup += 32;
  }

#pragma unroll 1
  for (int kt = 0; kt < NT - 3; ++kt)    // kt=0..60, stages tile kt+3
    g1_tile<8, true>(SM + (kt & 3) * 16384, ab0, bb0, ap0, ap1, bgp, bup,
                     SM + ((kt + 3) & 3) * 16384 + t * 8, accg, accu);
  g1_tile<8, false>(SM + ((NT - 3) & 3) * 16384, ab0, bb0, ap0, ap1, bgp, bup, SM, accg, accu);
  g1_tile<4, false>(SM + ((NT - 2) & 3) * 16384, ab0, bb0, ap0, ap1, bgp, bup, SM, accg, accu);
  g1_tile<0, false>(SM + ((NT - 1) & 3) * 16384, ab0, bb0, ap0, ap1, bgp, bup, SM, accg, accu);

  // Epilogue: silu(g)*u -> bf16 out-tile in LDS (stride 136), coalesced stores.
  // Out-tile uses SM[0..34816) — disjoint from slot 3 (>=49152) still being read.
  const int quad = lane >> 4;
#pragma unroll
  for (int i = 0; i < 8; ++i)
#pragma unroll
    for (int j = 0; j < 2; ++j)
#pragma unroll
      for (int r = 0; r < 4; ++r) {
        int row = wm * 128 + i * 16 + quad * 4 + r;
        int col = wn * 32 + j * 16 + l15;
        float g = accg[i][j][r];
        float u = accu[i][j][r];
        float sv = g / (1.0f + __expf(-g));
        SM[row * 136 + col] = f2bf(sv * u);
      }
  __syncthreads();
  unsigned short* ip = inter + ((size_t)e * ME + m0) * IDIM + c0;
#pragma unroll
  for (int p = 0; p < 8; ++p) {
    int idx = p * 512 + t;               // 4096 uint4s: 256 rows x 16 parts
    int row = idx >> 4, part = idx & 15;
    *(uint4*)(ip + (size_t)row * IDIM + part * 8) = *(const uint4*)(SM + row * 136 + part * 8);
  }
}

// ---- Kernel 4 tile body: GEMM2 (256x256 tile) ----
template<int VMN, bool STG>
__device__ __forceinline__ void g2_tile(const unsigned short* S, int ab0, int bb0,
                                        const unsigned short*& ap0, const unsigned short*& ap1,
                                        const unsigned short*& bp0, const unsigned short*& bp1,
                                        unsigned short* sb, f32x4 (&acc)[8][4]) {
  wait_vmcnt<VMN>();
  __builtin_amdgcn_s_barrier();
  asm volatile("" ::: "memory");
  bf16x8 a[4], b[4];
#pragma unroll
  for (int i = 0; i < 4; ++i) a[i] = *(const bf16x8*)(S + ab0 + i * 512);
#pragma unroll
  for (int j = 0; j < 4; ++j) b[j] = *(const bf16x8*)(S + bb0 + j * 512);
  if constexpr (STG) { gld16(ap0, sb); gld16(ap1, sb + 4096); }
  __builtin_amdgcn_s_setprio(1);
#pragma unroll
  for (int i = 0; i < 4; ++i)
#pragma unroll
    for (int j = 0; j < 4; ++j)
      acc[i][j] = __builtin_amdgcn_mfma_f32_16x16x32_bf16(a[i], b[j], acc[i][j], 0, 0, 0);
  __builtin_amdgcn_s_setprio(0);
  bf16x8 a2[4];
#pragma unroll
  for (int i = 0; i < 4; ++i) a2[i] = *(const bf16x8*)(S + ab0 + (i + 4) * 512);
  if constexpr (STG) {
    gld16(bp0, sb + 8192); gld16(bp1, sb + 12288);
    ap0 += 32; ap1 += 32; bp0 += 32; bp1 += 32;
  }
  __builtin_amdgcn_s_setprio(1);
#pragma unroll
  for (int i = 0; i < 4; ++i)
#pragma unroll
    for (int j = 0; j < 4; ++j)
      acc[i + 4][j] = __builtin_amdgcn_mfma_f32_16x16x32_bf16(a2[i], b[j], acc[i + 4][j], 0, 0, 0);
  __builtin_amdgcn_s_setprio(0);
}

// ---- Kernel 4: GEMM2, 256x256 block, scattered fp32 output rows ----
__global__ void __launch_bounds__(512) gemm2(const unsigned short* __restrict__ inter,
                                             const unsigned short* __restrict__ w2t,
                                             float* __restrict__ out) {
  __shared__ unsigned short SM[65536];
  const int e = blockIdx.z;
  const int m0 = blockIdx.x * 256;
  const int n0 = blockIdx.y * 256;
  const int t = threadIdx.x;
  const int lane = t & 63;
  const int wave = t >> 6;
  const int wm = wave >> 2;              // 0..1
  const int wn = wave & 3;               // 0..3 : 64-col quarter

  const unsigned short* ae = inter + (size_t)e * ME * IDIM;
  const unsigned short* be = w2t + (size_t)e * HDIM * IDIM;

  const int srow = t >> 2;
  const int scol = ((t & 3) * 8) ^ ((t & 32) ? 16 : 0);
  const unsigned short* ap0 = ae + (size_t)(m0 + srow) * IDIM + scol;
  const unsigned short* ap1 = ap0 + (size_t)128 * IDIM;
  const unsigned short* bp0 = be + (size_t)(n0 + srow) * IDIM + scol;
  const unsigned short* bp1 = bp0 + (size_t)128 * IDIM;

  const int l15 = lane & 15;
  const int kqs = ((lane >> 4) * 8) ^ ((lane & 8) ? 16 : 0);
  const int ab0 = (wm * 128 + l15) * 32 + kqs;
  const int bb0 = 8192 + (wn * 64 + l15) * 32 + kqs;

  f32x4 acc[8][4] = {};

#pragma unroll
  for (int s = 0; s < 3; ++s) {
    unsigned short* sb = SM + s * 16384 + t * 8;
    gld16(ap0, sb); gld16(ap1, sb + 4096); gld16(bp0, sb + 8192); gld16(bp1, sb + 12288);
    ap0 += 32; ap1 += 32; bp0 += 32; bp1 += 32;
  }

#pragma unroll 1
  for (int kt = 0; kt < NT - 3; ++kt)
    g2_tile<8, true>(SM + (kt & 3) * 16384, ab0, bb0, ap0, ap1, bp0, bp1,
                     SM + ((kt + 3) & 3) * 16384 + t * 8, acc);
  g2_tile<8, false>(SM + ((NT - 3) & 3) * 16384, ab0, bb0, ap0, ap1, bp0, bp1, SM, acc);
  g2_tile<4, false>(SM + ((NT - 2) & 3) * 16384, ab0, bb0, ap0, ap1, bp0, bp1, SM, acc);
  g2_tile<0, false>(SM + ((NT - 1) & 3) * 16384, ab0, bb0, ap0, ap1, bp0, bp1, SM, acc);

  // scatter rows: expert-grouped row t -> out row b*2048 + g*4 + e
  const int quad = lane >> 4;
#pragma unroll
  for (int i = 0; i < 8; ++i)
#pragma unroll
    for (int r = 0; r < 4; ++r) {
      int trow = m0 + wm * 128 + i * 16 + quad * 4 + r;
      int b_ = trow >> 9, g_ = trow & 511;
      float* orow = out + ((size_t)((b_ << 11) + (g_ << 2) + e)) * HDIM + n0 + wn * 64;
#pragma unroll
      for (int j = 0; j < 4; ++j) orow[j * 16 + l15] = acc[i][j][r];
    }
}

extern "C" void kernel_launch(void* const* d_in, const int* in_sizes, int n_in,
                              void* d_out, int out_size, void* d_ws, size_t ws_size,
                              hipStream_t stream) {
  (void)in_sizes; (void)n_in; (void)out_size; (void)ws_size;
  const float* x  = (const float*)d_in[0];
  const float* w1 = (const float*)d_in[1];
  const float* w2 = (const float*)d_in[2];
  float* out = (float*)d_out;

  char* ws = (char*)d_ws;
  unsigned short* xb    = (unsigned short*)(ws);
  unsigned short* w1t   = (unsigned short*)(ws + 67108864);
  unsigned short* w2t   = (unsigned short*)(ws + 134217728);
  unsigned short* inter = (unsigned short*)(ws + 167772160);

  pack_x<<<16384, 256, 0, stream>>>(x, xb);
  transpose_cvt<<<dim3(128, 64, 4), 256, 0, stream>>>(w1, w1t, 2048, 4096);
  transpose_cvt<<<dim3(64, 64, 4), 256, 0, stream>>>(w2, w2t, 2048, 2048);
  gemm1_silu<<<dim3(16, 16, 4), 512, 0, stream>>>(xb, w1t, inter);
  gemm2<<<dim3(16, 8, 4), 512, 0, stream>>>(inter, w2t, out);
}